// Round 8
// baseline (152.033 us; speedup 1.0000x reference)
//
#include <hip/hip_runtime.h>

#define TOTAL_B   131072
#define IN_FEATS  32
#define STATE     128
#define KDIM      160            // STATE + IN_FEATS
#define THREADS   1024           // 16 waves, one block per CU
#define GRID      256
#define ROWS_PER_BLOCK (TOTAL_B / GRID)       // 512
#define ROWS_PER_WAVE  (ROWS_PER_BLOCK / 16)  // 32 = 2 groups of 16
#define NFRAG     120            // 8 slices x 3 gate-blocks x 5 k-steps
#define WLDS_BYTES (NFRAG * 64 * 16)          // 122880 B

typedef __bf16 bf16x8 __attribute__((ext_vector_type(8)));
typedef float  f32x4  __attribute__((ext_vector_type(4)));

__device__ __forceinline__ float fsigmoid(float x) { return 1.0f / (1.0f + __expf(-x)); }
__device__ __forceinline__ float ftanh(float x)    { return 2.0f / (1.0f + __expf(-2.0f * x)) - 1.0f; }

// Barrier-free streaming LLTM: W lives in LDS in MFMA-fragment order; each wave
// independently owns 32 batch rows. A = X (row = lane&15 = batch), B = W^T
// (col = lane&15 = gate), D: col = gate, row = (lane>>4)*4+j = batch row.
__global__ __launch_bounds__(THREADS, 4) void lltm_fused(
    const float* __restrict__ xin,       // [B,32]
    const float* __restrict__ old_h,     // [B,128]
    const float* __restrict__ old_cell,  // [B,128]
    const float* __restrict__ Wt,        // [384,160]
    const float* __restrict__ bias,      // [384]
    float* __restrict__ out)             // new_h [B,128] then new_cell [B,128]
{
    __shared__ __align__(128) char wlds[WLDS_BYTES];

    const int t    = threadIdx.x;
    const int lane = t & 63;
    const int wid  = t >> 6;             // 0..15
    const int l15  = lane & 15;
    const int lg   = lane >> 4;          // 0..3

    // ---- one-time: W -> LDS in fragment order (read side is lane-contiguous) ----
    // chunk c = frag*64 + lane, frag = (slice*3 + gt)*5 + ks
    // holds bf16x8 of W[gate = gt*128 + slice*16 + (lane&15)][k = ks*32 + (lane>>4)*8 ..+8]
    #pragma unroll
    for (int i = 0; i < 8; ++i) {
        int c = t + i * THREADS;
        if (c < NFRAG * 64) {
            int ln = c & 63, frag = c >> 6;
            int ks = frag % 5, gtile = frag / 5;
            int slice = gtile / 3, gt = gtile - 3 * slice;
            int gate = gt * STATE + slice * 16 + (ln & 15);
            int k0 = ks * 32 + (ln >> 4) * 8;
            const float* p = Wt + (size_t)gate * KDIM + k0;
            f32x4 lo = *(const f32x4*)p;
            f32x4 hi = *((const f32x4*)p + 1);
            bf16x8 v;
            #pragma unroll
            for (int j = 0; j < 4; ++j) { v[j] = (__bf16)lo[j]; v[j + 4] = (__bf16)hi[j]; }
            *(bf16x8*)(wlds + (size_t)c * 16) = v;
        }
    }
    __syncthreads();   // the only barrier

    // ---- this wave's 32 batch rows ----
    const long r0 = (long)blockIdx.x * ROWS_PER_BLOCK + (long)wid * ROWS_PER_WAVE;

    // A fragments: X = [old_h | xin], row = l15 within group, k-chunk = lg*8
    bf16x8 af[2][5];
    #pragma unroll
    for (int grp = 0; grp < 2; ++grp) {
        const long r = r0 + grp * 16 + l15;
        const float* ph = old_h + r * (long)STATE + lg * 8;
        const float* px = xin + r * (long)IN_FEATS + lg * 8;
        #pragma unroll
        for (int ks = 0; ks < 5; ++ks) {
            const float* p = (ks < 4) ? (ph + ks * 32) : px;
            f32x4 lo = *(const f32x4*)p;
            f32x4 hi = *((const f32x4*)p + 1);
            bf16x8 v;
            #pragma unroll
            for (int j = 0; j < 4; ++j) { v[j] = (__bf16)lo[j]; v[j + 4] = (__bf16)hi[j]; }
            af[grp][ks] = v;
        }
    }

    // ---- 8 gate-slices, fully independent of other waves ----
    #pragma unroll
    for (int s = 0; s < 8; ++s) {
        const int sb = s * 16 + l15;     // this lane's state index
        const float bi = bias[sb];
        const float bo = bias[STATE + sb];
        const float bc = bias[2 * STATE + sb];

        // old_cell for this slice (issued before the MFMA chain; ~500 cyc of cover)
        float oc[2][4];
        #pragma unroll
        for (int grp = 0; grp < 2; ++grp)
            #pragma unroll
            for (int j = 0; j < 4; ++j)
                oc[grp][j] = old_cell[(r0 + grp * 16 + lg * 4 + j) * (long)STATE + sb];

        f32x4 aig[2], aog[2], acc[2];
        #pragma unroll
        for (int grp = 0; grp < 2; ++grp) {
            aig[grp] = (f32x4){0.f, 0.f, 0.f, 0.f};
            aog[grp] = (f32x4){0.f, 0.f, 0.f, 0.f};
            acc[grp] = (f32x4){0.f, 0.f, 0.f, 0.f};
        }

        // B-frag double buffer: 3 reads per k-step, prefetched one step ahead
        bf16x8 bf0[3], bf1[3];
        #pragma unroll
        for (int gt = 0; gt < 3; ++gt)
            bf0[gt] = *(const bf16x8*)(wlds + (size_t)(((s * 3 + gt) * 5 + 0) * 64 + lane) * 16);
        #pragma unroll
        for (int ks = 0; ks < 5; ++ks) {
            bf16x8* cur = (ks & 1) ? bf1 : bf0;
            bf16x8* nxt = (ks & 1) ? bf0 : bf1;
            if (ks < 4) {
                #pragma unroll
                for (int gt = 0; gt < 3; ++gt)
                    nxt[gt] = *(const bf16x8*)(wlds + (size_t)(((s * 3 + gt) * 5 + ks + 1) * 64 + lane) * 16);
            }
            #pragma unroll
            for (int grp = 0; grp < 2; ++grp) {
                aig[grp] = __builtin_amdgcn_mfma_f32_16x16x32_bf16(af[grp][ks], cur[0], aig[grp], 0, 0, 0);
                aog[grp] = __builtin_amdgcn_mfma_f32_16x16x32_bf16(af[grp][ks], cur[1], aog[grp], 0, 0, 0);
                acc[grp] = __builtin_amdgcn_mfma_f32_16x16x32_bf16(af[grp][ks], cur[2], acc[grp], 0, 0, 0);
            }
        }

        // epilogue: lane owns gate sb for rows r0 + grp*16 + lg*4 + j
        #pragma unroll
        for (int grp = 0; grp < 2; ++grp) {
            #pragma unroll
            for (int j = 0; j < 4; ++j) {
                float ig = fsigmoid(aig[grp][j] + bi);
                float og = fsigmoid(aog[grp][j] + bo);
                float cp = acc[grp][j] + bc;
                float cc = cp > 0.f ? cp : (__expf(cp) - 1.0f);
                float c2 = oc[grp][j] + cc * ig;
                const long r = r0 + grp * 16 + lg * 4 + j;
                __builtin_nontemporal_store(ftanh(c2) * og, out + r * (long)STATE + sb);
                __builtin_nontemporal_store(c2, out + (long)TOTAL_B * STATE + r * (long)STATE + sb);
            }
        }
    }
}

extern "C" void kernel_launch(void* const* d_in, const int* in_sizes, int n_in,
                              void* d_out, int out_size, void* d_ws, size_t ws_size,
                              hipStream_t stream)
{
    const float* xin      = (const float*)d_in[0];
    const float* old_h    = (const float*)d_in[1];
    const float* old_cell = (const float*)d_in[2];
    const float* Wt       = (const float*)d_in[3];
    const float* bias     = (const float*)d_in[4];
    float* out = (float*)d_out;
    lltm_fused<<<GRID, THREADS, 0, stream>>>(xin, old_h, old_cell, Wt, bias, out);
}

// Round 9
// 114.515 us; speedup vs baseline: 1.3276x; 1.3276x over previous
//
#include <hip/hip_runtime.h>

#define TOTAL_B   131072
#define IN_FEATS  32
#define STATE     128
#define KDIM      160            // STATE + IN_FEATS
#define BROWS     64             // batch rows per tile
#define THREADS   512            // 8 waves
#define LDSROW    384            // bytes per X LDS row (160 bf16 = 320B, padded)
#define GRID      (TOTAL_B / BROWS)   // 2048 blocks, one tile each

typedef __bf16 bf16x8 __attribute__((ext_vector_type(8)));
typedef float  f32x4  __attribute__((ext_vector_type(4)));

__device__ __forceinline__ float fsigmoid(float x) { return 1.0f / (1.0f + __expf(-x)); }
__device__ __forceinline__ float ftanh(float x)    { return 2.0f / (1.0f + __expf(-2.0f * x)) - 1.0f; }

struct Xregs {
    f32x4 hlo[2], hhi[2];   // old_h tile chunks
    f32x4 xlo, xhi;         // xin tile chunk (threads < 256)
};

// Issue global loads for tile at batch base b0 into registers (no waiting).
__device__ __forceinline__ void issue_x(const float* __restrict__ old_h,
                                        const float* __restrict__ xin,
                                        long b0, int t, Xregs& r)
{
    #pragma unroll
    for (int i = 0; i < 2; ++i) {
        int c   = t + i * THREADS;           // 0..1023 chunks of 8 floats
        int row = c >> 4;
        int kc  = (c & 15) * 8;
        const float* p = old_h + (b0 + row) * (long)STATE + kc;
        r.hlo[i] = *(const f32x4*)p;
        r.hhi[i] = *((const f32x4*)p + 1);
    }
    if (t < 256) {
        int row = t >> 2;
        int kc  = (t & 3) * 8;
        const float* p = xin + (b0 + row) * (long)IN_FEATS + kc;
        r.xlo = *(const f32x4*)p;
        r.xhi = *((const f32x4*)p + 1);
    }
}

// Convert staged registers to bf16 and write into LDS (swizzled rows).
__device__ __forceinline__ void write_x(char* smem, int t, const Xregs& r)
{
    #pragma unroll
    for (int i = 0; i < 2; ++i) {
        int c   = t + i * THREADS;
        int row = c >> 4;
        int kc  = (c & 15) * 8;
        bf16x8 v;
        #pragma unroll
        for (int j = 0; j < 4; ++j) { v[j] = (__bf16)r.hlo[i][j]; v[j + 4] = (__bf16)r.hhi[i][j]; }
        int off = row * LDSROW + kc * 2;
        off ^= (row & 7) << 4;
        *(bf16x8*)(smem + off) = v;
    }
    if (t < 256) {
        int row = t >> 2;
        int kc  = (t & 3) * 8;
        bf16x8 v;
        #pragma unroll
        for (int j = 0; j < 4; ++j) { v[j] = (__bf16)r.xlo[j]; v[j + 4] = (__bf16)r.xhi[j]; }
        int off = row * LDSROW + (STATE + kc) * 2;
        off ^= (row & 7) << 4;
        *(bf16x8*)(smem + off) = v;
    }
}

__global__ __launch_bounds__(THREADS, 2) void lltm_fused(
    const float* __restrict__ xin,       // [B,32]
    const float* __restrict__ old_h,     // [B,128]
    const float* __restrict__ old_cell,  // [B,128]
    const float* __restrict__ Wt,        // [384,160]
    const float* __restrict__ bias,      // [384]
    float* __restrict__ out)             // new_h [B,128] then new_cell [B,128]
{
    __shared__ __align__(128) char smem[BROWS * LDSROW];   // 24 KB, single buffer

    const int t    = threadIdx.x;
    const int lane = t & 63;
    const int wv   = t >> 6;            // wave 0..7: owns gate-state slice [16*wv, 16*wv+16)
    const int l15  = lane & 15;
    const int lg   = lane >> 4;         // 0..3
    const int sbase = 16 * wv + 4 * lg; // this lane's 4 gate-state rows
    const long b0  = (long)blockIdx.x * BROWS;

    // ---- issue this tile's X loads first (earliest arrival) ----
    Xregs xr;
    issue_x(old_h, xin, b0, t, xr);

    // ---- old_cell: in flight during staging + MFMA phases ----
    f32x4 oc[4];
    #pragma unroll
    for (int sub = 0; sub < 4; ++sub)
        oc[sub] = *(const f32x4*)(old_cell + (b0 + sub * 16 + l15) * (long)STATE + sbase);

    // ---- A fragments (weights as bf16), 3 gate blocks x 5 K-steps; L2-hot ----
    bf16x8 afrag[3][5];
    {
        const int g_lo = 16 * wv + l15;
        #pragma unroll
        for (int gt = 0; gt < 3; ++gt) {
            #pragma unroll
            for (int ks = 0; ks < 5; ++ks) {
                const float* p = Wt + (size_t)(gt * STATE + g_lo) * KDIM + ks * 32 + lg * 8;
                f32x4 lo = *(const f32x4*)p;
                f32x4 hi = *(const f32x4*)(p + 4);
                bf16x8 a;
                #pragma unroll
                for (int i = 0; i < 4; ++i) { a[i] = (__bf16)lo[i]; a[i + 4] = (__bf16)hi[i]; }
                afrag[gt][ks] = a;
            }
        }
    }
    const f32x4 b_ig = *(const f32x4*)(bias + sbase);
    const f32x4 b_og = *(const f32x4*)(bias + STATE + sbase);
    const f32x4 b_cc = *(const f32x4*)(bias + 2 * STATE + sbase);

    // ---- stage X tile (regs -> bf16 -> LDS) ----
    write_x(smem, t, xr);

    // ONE barrier: drain LDS writes only (lgkmcnt); no vmcnt(0) drain.
    asm volatile("s_waitcnt lgkmcnt(0)\n\ts_barrier" ::: "memory");

    #pragma unroll
    for (int sub = 0; sub < 4; ++sub) {
        const int brow = sub * 16 + l15;     // B layout: col = lane&15 (batch row)
        f32x4 acc_ig = {0.f, 0.f, 0.f, 0.f};
        f32x4 acc_og = {0.f, 0.f, 0.f, 0.f};
        f32x4 acc_cc = {0.f, 0.f, 0.f, 0.f};
        #pragma unroll
        for (int ks = 0; ks < 5; ++ks) {
            int off = brow * LDSROW + (ks * 32 + lg * 8) * 2;
            off ^= (brow & 7) << 4;
            bf16x8 bfr = *(const bf16x8*)(smem + off);
            acc_ig = __builtin_amdgcn_mfma_f32_16x16x32_bf16(afrag[0][ks], bfr, acc_ig, 0, 0, 0);
            acc_og = __builtin_amdgcn_mfma_f32_16x16x32_bf16(afrag[1][ks], bfr, acc_og, 0, 0, 0);
            acc_cc = __builtin_amdgcn_mfma_f32_16x16x32_bf16(afrag[2][ks], bfr, acc_cc, 0, 0, 0);
        }
        // lane holds batch row (b0 + sub*16 + l15), gate-states sbase..sbase+3
        const long bg = b0 + sub * 16 + l15;
        f32x4 nh, nc;
        #pragma unroll
        for (int j = 0; j < 4; ++j) {
            float ig = fsigmoid(acc_ig[j] + b_ig[j]);
            float og = fsigmoid(acc_og[j] + b_og[j]);
            float cp = acc_cc[j] + b_cc[j];
            float cc = cp > 0.f ? cp : (__expf(cp) - 1.0f);
            float c2 = oc[sub][j] + cc * ig;
            nc[j] = c2;
            nh[j] = ftanh(c2) * og;
        }
        // nt stores: 8 waves cover each line's chunks near-simultaneously (merge OK),
        // and no-allocate protects L3 input residency (R7 lesson).
        __builtin_nontemporal_store(nh, (f32x4*)(out + bg * STATE + sbase));
        __builtin_nontemporal_store(nc, (f32x4*)(out + (long)TOTAL_B * STATE + bg * STATE + sbase));
    }
}

extern "C" void kernel_launch(void* const* d_in, const int* in_sizes, int n_in,
                              void* d_out, int out_size, void* d_ws, size_t ws_size,
                              hipStream_t stream)
{
    const float* xin      = (const float*)d_in[0];
    const float* old_h    = (const float*)d_in[1];
    const float* old_cell = (const float*)d_in[2];
    const float* Wt       = (const float*)d_in[3];
    const float* bias     = (const float*)d_in[4];
    float* out = (float*)d_out;
    lltm_fused<<<GRID, THREADS, 0, stream>>>(xin, old_h, old_cell, Wt, bias, out);
}

// Round 10
// 86.728 us; speedup vs baseline: 1.7530x; 1.3204x over previous
//
#include <hip/hip_runtime.h>

#define TOTAL_B   131072
#define IN_FEATS  32
#define STATE     128
#define KDIM      160            // STATE + IN_FEATS
#define BROWS     64             // batch rows per tile
#define THREADS   512            // 8 waves
#define LDSROW    256            // bytes per LDS row: 128 bf16 (old_h only)
#define GRID      512
#define ITERS     ((TOTAL_B / BROWS) / GRID)    // 4

typedef __bf16 bf16x8 __attribute__((ext_vector_type(8)));
typedef float  f32x4  __attribute__((ext_vector_type(4)));

__device__ __forceinline__ float fsigmoid(float x) { return 1.0f / (1.0f + __expf(-x)); }
__device__ __forceinline__ float ftanh(float x)    { return 2.0f / (1.0f + __expf(-2.0f * x)) - 1.0f; }

struct Hregs { f32x4 lo[2], hi[2]; };   // 16 VGPR: old_h tile chunks only

// Issue old_h loads for tile at batch base b0 into registers (no waiting).
__device__ __forceinline__ void issue_h(const float* __restrict__ old_h,
                                        long b0, int t, Hregs& r)
{
    #pragma unroll
    for (int i = 0; i < 2; ++i) {
        int c   = t + i * THREADS;           // 0..1023 chunks of 8 floats
        int row = c >> 4;                    // 0..63
        int kc  = (c & 15) * 8;              // 0..120
        const float* p = old_h + (b0 + row) * (long)STATE + kc;
        r.lo[i] = *(const f32x4*)p;
        r.hi[i] = *((const f32x4*)p + 1);
    }
}

// Convert staged registers to bf16 and write into LDS (swizzled rows).
__device__ __forceinline__ void write_h(char* smem, int t, const Hregs& r)
{
    #pragma unroll
    for (int i = 0; i < 2; ++i) {
        int c   = t + i * THREADS;
        int row = c >> 4;
        int kc  = (c & 15) * 8;
        bf16x8 v;
        #pragma unroll
        for (int j = 0; j < 4; ++j) { v[j] = (__bf16)r.lo[i][j]; v[j + 4] = (__bf16)r.hi[i][j]; }
        int off = row * LDSROW + kc * 2;
        off ^= (row & 7) << 4;
        *(bf16x8*)(smem + off) = v;
    }
}

__global__ __launch_bounds__(THREADS, 3) void lltm_fused(
    const float* __restrict__ xin,       // [B,32]
    const float* __restrict__ old_h,     // [B,128]
    const float* __restrict__ old_cell,  // [B,128]
    const float* __restrict__ Wt,        // [384,160]
    const float* __restrict__ bias,      // [384]
    float* __restrict__ out)             // new_h [B,128] then new_cell [B,128]
{
    __shared__ __align__(128) char smem[2][BROWS * LDSROW];   // 32 KB double buffer

    const int t    = threadIdx.x;
    const int lane = t & 63;
    const int wv   = t >> 6;            // wave 0..7: owns gate-state slice [16*wv, 16*wv+16)
    const int l15  = lane & 15;
    const int lg   = lane >> 4;         // 0..3
    const int sbase = 16 * wv + 4 * lg; // this lane's 4 gate-state rows

    // ---- software pipeline: old_h double-buffered in registers ----
    Hregs xr[2];
    issue_h(old_h, (long)blockIdx.x * BROWS, t, xr[0]);

    // ---- persistent A fragments (weights as bf16), 3 gate blocks x 5 K-steps ----
    bf16x8 afrag[3][5];
    {
        const int g_lo = 16 * wv + l15;
        #pragma unroll
        for (int gt = 0; gt < 3; ++gt) {
            #pragma unroll
            for (int ks = 0; ks < 5; ++ks) {
                const float* p = Wt + (size_t)(gt * STATE + g_lo) * KDIM + ks * 32 + lg * 8;
                f32x4 lo = *(const f32x4*)p;
                f32x4 hi = *(const f32x4*)(p + 4);
                bf16x8 a;
                #pragma unroll
                for (int i = 0; i < 4; ++i) { a[i] = (__bf16)lo[i]; a[i + 4] = (__bf16)hi[i]; }
                afrag[gt][ks] = a;
            }
        }
    }
    const f32x4 b_ig = *(const f32x4*)(bias + sbase);
    const f32x4 b_og = *(const f32x4*)(bias + STATE + sbase);
    const f32x4 b_cc = *(const f32x4*)(bias + 2 * STATE + sbase);

    #pragma unroll
    for (int it = 0; it < ITERS; ++it) {
        const long b0 = ((long)blockIdx.x + (long)it * GRID) * BROWS;

        // stage current old_h tile (regs -> bf16 -> LDS)
        write_h(smem[it & 1], t, xr[it & 1]);

        // prefetch NEXT tile's old_h into the other register buffer
        if (it + 1 < ITERS)
            issue_h(old_h, ((long)blockIdx.x + (long)(it + 1) * GRID) * BROWS,
                    t, xr[(it + 1) & 1]);

        // ONE barrier per iter: drain LDS ops only; reg-dest global loads stay in flight.
        asm volatile("s_waitcnt lgkmcnt(0)\n\ts_barrier" ::: "memory");

        // old_cell for THIS tile: issued at compute-phase start (covered by MFMA chains)
        f32x4 oc[4];
        #pragma unroll
        for (int sub = 0; sub < 4; ++sub)
            oc[sub] = *(const f32x4*)(old_cell + (b0 + sub * 16 + l15) * (long)STATE + sbase);

        const char* sbuf = smem[it & 1];
        #pragma unroll
        for (int sub = 0; sub < 4; ++sub) {
            const int brow = sub * 16 + l15;     // B layout: col = lane&15 (batch row)
            const long bg  = b0 + brow;

            // ks=4 B-fragment (xin) straight from global: 16 full 128B lines per
            // wave-instr, L1-hot across the block's 8 waves. Issued before the MFMA
            // chain so ~12 MFMA + 4 ds_read cover most of its latency.
            const float* px = xin + bg * (long)IN_FEATS + lg * 8;
            f32x4 xlo = *(const f32x4*)px;
            f32x4 xhi = *((const f32x4*)px + 1);
            bf16x8 bx;
            #pragma unroll
            for (int j = 0; j < 4; ++j) { bx[j] = (__bf16)xlo[j]; bx[j + 4] = (__bf16)xhi[j]; }

            f32x4 acc_ig = {0.f, 0.f, 0.f, 0.f};
            f32x4 acc_og = {0.f, 0.f, 0.f, 0.f};
            f32x4 acc_cc = {0.f, 0.f, 0.f, 0.f};
            #pragma unroll
            for (int ks = 0; ks < 5; ++ks) {
                bf16x8 bfr;
                if (ks < 4) {
                    int off = brow * LDSROW + (ks * 32 + lg * 8) * 2;
                    off ^= (brow & 7) << 4;
                    bfr = *(const bf16x8*)(sbuf + off);
                } else {
                    bfr = bx;
                }
                acc_ig = __builtin_amdgcn_mfma_f32_16x16x32_bf16(afrag[0][ks], bfr, acc_ig, 0, 0, 0);
                acc_og = __builtin_amdgcn_mfma_f32_16x16x32_bf16(afrag[1][ks], bfr, acc_og, 0, 0, 0);
                acc_cc = __builtin_amdgcn_mfma_f32_16x16x32_bf16(afrag[2][ks], bfr, acc_cc, 0, 0, 0);
            }

            // epilogue: lane holds batch row bg, gate-states sbase..sbase+3
            f32x4 nh, nc;
            #pragma unroll
            for (int j = 0; j < 4; ++j) {
                float ig = fsigmoid(acc_ig[j] + b_ig[j]);
                float og = fsigmoid(acc_og[j] + b_og[j]);
                float cp = acc_cc[j] + b_cc[j];
                float cc = cp > 0.f ? cp : (__expf(cp) - 1.0f);
                float c2 = oc[sub][j] + cc * ig;
                nc[j] = c2;
                nh[j] = ftanh(c2) * og;
            }
            __builtin_nontemporal_store(nh, (f32x4*)(out + bg * STATE + sbase));
            __builtin_nontemporal_store(nc, (f32x4*)(out + (long)TOTAL_B * STATE + bg * STATE + sbase));
        }
        // no trailing barrier: double buffer + next iter's pre-compute barrier cover WAR
    }
}

extern "C" void kernel_launch(void* const* d_in, const int* in_sizes, int n_in,
                              void* d_out, int out_size, void* d_ws, size_t ws_size,
                              hipStream_t stream)
{
    const float* xin      = (const float*)d_in[0];
    const float* old_h    = (const float*)d_in[1];
    const float* old_cell = (const float*)d_in[2];
    const float* Wt       = (const float*)d_in[3];
    const float* bias     = (const float*)d_in[4];
    float* out = (float*)d_out;
    lltm_fused<<<GRID, THREADS, 0, stream>>>(xin, old_h, old_cell, Wt, bias, out);
}